// Round 5
// baseline (704.627 us; speedup 1.0000x reference)
//
#include <hip/hip_runtime.h>
#include <cstdint>
#include <cstddef>

#define DIMN 2048
#define SEQ  2048
#define NB   2
#define NH   16
#define DH   128

typedef __bf16 bf16x8 __attribute__((ext_vector_type(8)));
typedef float  f32x4  __attribute__((ext_vector_type(4)));
typedef bf16x8 __attribute__((may_alias)) bf16x8_a;
typedef ushort4 __attribute__((may_alias)) ushort4_a;
typedef float4 __attribute__((may_alias)) float4_a;

// ---- bf16 <-> f32 helpers on raw ushort storage (RNE, matches np/jnp) ----
__device__ __forceinline__ float b2f(unsigned short b) {
    unsigned u = ((unsigned)b) << 16; float f; __builtin_memcpy(&f, &u, 4); return f;
}
__device__ __forceinline__ unsigned short f2b(float f) {
    unsigned u; __builtin_memcpy(&u, &f, 4);
    u = (u + 0x7FFFu + ((u >> 16) & 1u)) >> 16;
    return (unsigned short)u;
}
__device__ __forceinline__ __bf16 f2bf(float f) {
    unsigned short us = f2b(f); __bf16 h; __builtin_memcpy(&h, &us, 2); return h;
}

// dtype flag: freqs_cos[0] == 1.0 exactly. fp32 word0 = 0x3F800000;
// bf16 word0 = 0x3F80 | 0x3F80<<16 = 0x3F803F80. Uniform, deterministic.
__device__ __forceinline__ bool dt_is_f32(const void* fc) {
    return ((const unsigned int*)fc)[0] == 0x3F800000u;
}

// async global->LDS, 16B per lane (LDS dest = wave-uniform base + lane*16)
__device__ __forceinline__ void gload_lds16(const unsigned short* g, unsigned short* l) {
    __builtin_amdgcn_global_load_lds(
        (const __attribute__((address_space(1))) void*)g,
        (__attribute__((address_space(3))) void*)l,
        16, 0, 0);
}

// fp32 global -> bf16 LDS staging: 8 floats -> bf16x8 (RNE)
__device__ __forceinline__ void stage32(const float* g, unsigned short* l) {
    float4 lo = *(const float4_a*)g;
    float4 hi = *(const float4_a*)(g + 4);
    bf16x8 v;
    v[0] = f2bf(lo.x); v[1] = f2bf(lo.y); v[2] = f2bf(lo.z); v[3] = f2bf(lo.w);
    v[4] = f2bf(hi.x); v[5] = f2bf(hi.y); v[6] = f2bf(hi.z); v[7] = f2bf(hi.w);
    *(bf16x8_a*)l = v;
}

// =====================================================================
// Generic "bt" GEMM:  C[m,n] = scale * sum_k A[m,k]*B[n,k]  (fp32 acc)
// A row-major [M,K] stride lda; B row-major [N,K] stride ldb; C row-major ldc.
// amode/bmode/cmode: 1 = dtype follows runtime flag (fp32 or bf16), 0 = bf16 always.
// grid.z -> (zb,zh) = (z/Hz, z%Hz). M,N mult of 128; K mult of 32.  (m97 structure)
// =====================================================================
__global__ __launch_bounds__(256, 2) void gemm_bt(
    const void* __restrict__ A, const void* __restrict__ B, void* __restrict__ C,
    const void* __restrict__ dt, int amode, int bmode, int cmode,
    int K, int lda, int ldb, int ldc, int Hz,
    long long sAb, long long sAh, long long sBb, long long sBh,
    long long sCb, long long sCh, float scale)
{
    const bool isf32 = dt_is_f32(dt);
    const bool af32 = amode && isf32, bf32 = bmode && isf32, cf32 = cmode && isf32;

    int bx = blockIdx.x, by = blockIdx.y, z = blockIdx.z;
    int zb = z / Hz, zh = z - zb * Hz;
    const long long aoffz = zb * sAb + zh * sAh;
    const long long boffz = zb * sBb + zh * sBh;
    const long long coffz = zb * sCb + zh * sCh;
    const int m0 = by * 128, n0 = bx * 128;

    __shared__ alignas(16) unsigned short sA[128 * 32];
    __shared__ alignas(16) unsigned short sB[128 * 32];

    const int tid  = threadIdx.x;
    const int lane = tid & 63, wave = tid >> 6;
    const int waveM = wave >> 1, waveN = wave & 1;

    const int rowA = tid >> 2;          // 0..63
    const int c8   = (tid & 3) << 3;    // 0,8,16,24

    // bf16-path source pointers
    const unsigned short* gA0 = (const unsigned short*)A + aoffz + (size_t)(m0 + rowA)      * lda + c8;
    const unsigned short* gA1 = (const unsigned short*)A + aoffz + (size_t)(m0 + rowA + 64) * lda + c8;
    const unsigned short* gB0 = (const unsigned short*)B + boffz + (size_t)(n0 + rowA)      * ldb + c8;
    const unsigned short* gB1 = (const unsigned short*)B + boffz + (size_t)(n0 + rowA + 64) * ldb + c8;
    // fp32-path source pointers
    const float* fA0 = (const float*)A + aoffz + (size_t)(m0 + rowA)      * lda + c8;
    const float* fA1 = (const float*)A + aoffz + (size_t)(m0 + rowA + 64) * lda + c8;
    const float* fB0 = (const float*)B + boffz + (size_t)(n0 + rowA)      * ldb + c8;
    const float* fB1 = (const float*)B + boffz + (size_t)(n0 + rowA + 64) * ldb + c8;

    unsigned short* lA0 = sA + tid * 8;
    unsigned short* lA1 = sA + 2048 + tid * 8;
    unsigned short* lB0 = sB + tid * 8;
    unsigned short* lB1 = sB + 2048 + tid * 8;

    f32x4 acc[4][4];
    #pragma unroll
    for (int i = 0; i < 4; i++)
        #pragma unroll
        for (int j = 0; j < 4; j++)
            acc[i][j] = (f32x4){0.f, 0.f, 0.f, 0.f};

    const int fr = lane & 15, fq = lane >> 4;
    const int aoff = (waveM * 64 + fr) * 32 + fq * 8;
    const int boff = (waveN * 64 + fr) * 32 + fq * 8;

    for (int kt = 0; kt < K; kt += 32) {
        if (af32) { stage32(fA0, lA0); stage32(fA1, lA1); }
        else      { gload_lds16(gA0, lA0); gload_lds16(gA1, lA1); }
        if (bf32) { stage32(fB0, lB0); stage32(fB1, lB1); }
        else      { gload_lds16(gB0, lB0); gload_lds16(gB1, lB1); }
        gA0 += 32; gA1 += 32; gB0 += 32; gB1 += 32;
        fA0 += 32; fA1 += 32; fB0 += 32; fB1 += 32;
        __syncthreads();

        bf16x8 af[4], bfr[4];
        #pragma unroll
        for (int mt = 0; mt < 4; mt++)
            af[mt] = *(const bf16x8_a*)(sA + aoff + mt * 16 * 32);
        #pragma unroll
        for (int nt = 0; nt < 4; nt++)
            bfr[nt] = *(const bf16x8_a*)(sB + boff + nt * 16 * 32);
        #pragma unroll
        for (int mt = 0; mt < 4; mt++)
            #pragma unroll
            for (int nt = 0; nt < 4; nt++)
                acc[mt][nt] = __builtin_amdgcn_mfma_f32_16x16x32_bf16(
                    af[mt], bfr[nt], acc[mt][nt], 0, 0, 0);
        __syncthreads();
    }

    // C/D layout: col = lane&15 (n side), row = (lane>>4)*4 + r (m side)
    const int crow0 = m0 + waveM * 64 + fq * 4;
    const int ccol0 = n0 + waveN * 64 + fr;
    #pragma unroll
    for (int mt = 0; mt < 4; mt++)
        #pragma unroll
        for (int nt = 0; nt < 4; nt++) {
            size_t base = (size_t)(crow0 + mt * 16) * ldc + (ccol0 + nt * 16);
            if (cf32) {
                float* Cz = (float*)C + coffz;
                #pragma unroll
                for (int r = 0; r < 4; r++)
                    Cz[base + (size_t)r * ldc] = acc[mt][nt][r] * scale;
            } else {
                unsigned short* Cz = (unsigned short*)C + coffz;
                #pragma unroll
                for (int r = 0; r < 4; r++)
                    Cz[base + (size_t)r * ldc] = f2b(acc[mt][nt][r] * scale);
            }
        }
}

// ============== RoPE in place on q_lin and k_lin [NB*SEQ, DIMN] bf16 ==============
__global__ void rope_kernel(unsigned short* q, unsigned short* k,
                            const void* __restrict__ fc,
                            const void* __restrict__ fs)
{
    const bool isf32 = dt_is_f32(fc);
    int idx = blockIdx.x * 256 + threadIdx.x;     // pair index
    unsigned short* p = blockIdx.y ? k : q;
    int row = idx >> 10;                          // [0, NB*SEQ)
    int e   = (idx & 1023) << 1;                  // even feature
    int s   = row & (SEQ - 1);
    int j   = (e & (DH - 1)) >> 1;                // [0,64)
    float c, sn;
    if (isf32) {
        c  = ((const float*)fc)[s * 64 + j];
        sn = ((const float*)fs)[s * 64 + j];
    } else {
        c  = b2f(((const unsigned short*)fc)[s * 64 + j]);
        sn = b2f(((const unsigned short*)fs)[s * 64 + j]);
    }
    size_t off = (size_t)row * DIMN + e;
    float xr = b2f(p[off]), xi = b2f(p[off + 1]);
    p[off]     = f2b(xr * c - xi * sn);
    p[off + 1] = f2b(xr * sn + xi * c);
}

// ============== per-batch 2048x2048 transpose: out[i][t] = in[t][i] (bf16 ws) ==============
__global__ void transpose_kernel(const unsigned short* __restrict__ in,
                                 unsigned short* __restrict__ out)
{
    __shared__ unsigned short tile[32][33];
    int b = blockIdx.z;
    const unsigned short* ib = in + (size_t)b * SEQ * DIMN;
    unsigned short*       ob = out + (size_t)b * SEQ * DIMN;
    int t0 = blockIdx.x << 5, i0 = blockIdx.y << 5;
    int c = threadIdx.x & 31, r0 = threadIdx.x >> 5;
    for (int r = r0; r < 32; r += 8)
        tile[r][c] = ib[(size_t)(t0 + r) * DIMN + i0 + c];
    __syncthreads();
    for (int r = r0; r < 32; r += 8)
        ob[(size_t)(i0 + r) * SEQ + t0 + c] = tile[c][r];
}

// =====================================================================
// Fused flash attention (causal); all IO is bf16 workspace. Identical to R4.
// Block: one (q-tile of 128 rows, b, h); wave w owns q rows [w*32, w*32+32).
// KV processed in tiles of 64. Writes ctxT[dh][s] (transposed) directly.
// =====================================================================
#define KPAD 136   // 128 + 8
#define VPAD 72    // 64 + 8
__global__ __launch_bounds__(256, 2) void flash_kernel(
    const unsigned short* __restrict__ q_lin,
    const unsigned short* __restrict__ k_lin,
    const unsigned short* __restrict__ vTg,
    unsigned short* __restrict__ ctxT)
{
    __shared__ alignas(16) __bf16 sK[64 * KPAD];    // K tile rows t, cols dh
    __shared__ alignas(16) __bf16 sV[DH * VPAD];    // V^T rows dh, cols t
    __shared__ alignas(16) __bf16 sP[128 * VPAD];   // P rows q-local, cols t

    const int qt = blockIdx.x;
    const int z  = blockIdx.y;
    const int b  = z >> 4, h = z & 15;

    const unsigned short* Qg = q_lin + ((size_t)(b * SEQ + qt * 128)) * DIMN + h * DH;
    const unsigned short* Kg = k_lin + (size_t)b * SEQ * DIMN + h * DH;
    const unsigned short* Vg = vTg  + (size_t)b * SEQ * DIMN + (size_t)h * DH * SEQ;
    unsigned short*       Cg = ctxT + (size_t)b * SEQ * DIMN + (size_t)h * DH * SEQ;

    const int tid  = threadIdx.x;
    const int lane = tid & 63, wave = tid >> 6;
    const int fr = lane & 15, fq = lane >> 4;

    // Q fragments (A-layout): row = wave*32 + mt*16 + fr, k = kt*32 + fq*8 + j
    bf16x8 qf[2][4];
    #pragma unroll
    for (int mt = 0; mt < 2; mt++)
        #pragma unroll
        for (int kt = 0; kt < 4; kt++)
            qf[mt][kt] = *(const bf16x8_a*)(Qg + (size_t)(wave * 32 + mt * 16 + fr) * DIMN + kt * 32 + fq * 8);

    f32x4 o_acc[2][8];
    #pragma unroll
    for (int mt = 0; mt < 2; mt++)
        #pragma unroll
        for (int nt = 0; nt < 8; nt++)
            o_acc[mt][nt] = (f32x4){0.f, 0.f, 0.f, 0.f};
    float m_st[2][4], l_st[2][4];
    #pragma unroll
    for (int mt = 0; mt < 2; mt++)
        #pragma unroll
        for (int r = 0; r < 4; r++) { m_st[mt][r] = -1e30f; l_st[mt][r] = 0.f; }

    const float scale = 0.08838834764831845f;
    const int jmax = 2 * qt + 2;   // t-tiles of 64, exactly covering t <= qt*128+127

    for (int jt = 0; jt < jmax; jt++) {
        __syncthreads();   // all waves done reading sK/sV from previous iter
        const unsigned short* Kt = Kg + (size_t)jt * 64 * DIMN;
        const unsigned short* Vt = Vg + jt * 64;
        // stage K tile: 64 rows x 128 cols = 1024 16B-chunks; 4 per thread
        #pragma unroll
        for (int i = 0; i < 4; i++) {
            int cc  = tid + i * 256;
            int row = cc >> 4, col = (cc & 15) << 3;
            *(bf16x8_a*)(sK + row * KPAD + col) = *(const bf16x8_a*)(Kt + (size_t)row * DIMN + col);
        }
        // stage V^T tile: 128 rows x 64 cols = 1024 chunks; 4 per thread
        #pragma unroll
        for (int i = 0; i < 4; i++) {
            int cc  = tid + i * 256;
            int row = cc >> 3, col = (cc & 7) << 3;
            *(bf16x8_a*)(sV + row * VPAD + col) = *(const bf16x8_a*)(Vt + (size_t)row * SEQ + col);
        }
        __syncthreads();   // staging complete

        // S = Q . K^T  (B-frag: n = t = nt*16+fr, k = kt*32+fq*8)
        f32x4 s_acc[2][4];
        #pragma unroll
        for (int mt = 0; mt < 2; mt++)
            #pragma unroll
            for (int nt = 0; nt < 4; nt++)
                s_acc[mt][nt] = (f32x4){0.f, 0.f, 0.f, 0.f};
        #pragma unroll
        for (int kt = 0; kt < 4; kt++) {
            bf16x8 kf[4];
            #pragma unroll
            for (int nt = 0; nt < 4; nt++)
                kf[nt] = *(const bf16x8_a*)(sK + (nt * 16 + fr) * KPAD + kt * 32 + fq * 8);
            #pragma unroll
            for (int mt = 0; mt < 2; mt++)
                #pragma unroll
                for (int nt = 0; nt < 4; nt++)
                    s_acc[mt][nt] = __builtin_amdgcn_mfma_f32_16x16x32_bf16(
                        qf[mt][kt], kf[nt], s_acc[mt][nt], 0, 0, 0);
        }

        // scale, then causal mask (only the last two t-tiles can cross the diagonal)
        #pragma unroll
        for (int mt = 0; mt < 2; mt++)
            #pragma unroll
            for (int nt = 0; nt < 4; nt++)
                #pragma unroll
                for (int r = 0; r < 4; r++)
                    s_acc[mt][nt][r] *= scale;
        if (jt >= 2 * qt) {
            #pragma unroll
            for (int mt = 0; mt < 2; mt++)
                #pragma unroll
                for (int nt = 0; nt < 4; nt++)
                    #pragma unroll
                    for (int r = 0; r < 4; r++) {
                        int srow = wave * 32 + mt * 16 + fq * 4 + r;             // local q row
                        int tcol = jt * 64 + nt * 16 + fr - qt * 128;            // t - qtile base
                        if (tcol > srow) s_acc[mt][nt][r] = -1e30f;
                    }
        }

        // online softmax (row reductions across fr lanes = xor bits 0..3)
        float al[2][4];
        #pragma unroll
        for (int mt = 0; mt < 2; mt++)
            #pragma unroll
            for (int r = 0; r < 4; r++) {
                float rm = s_acc[mt][0][r];
                #pragma unroll
                for (int nt = 1; nt < 4; nt++) rm = fmaxf(rm, s_acc[mt][nt][r]);
                rm = fmaxf(rm, __shfl_xor(rm, 1, 64));
                rm = fmaxf(rm, __shfl_xor(rm, 2, 64));
                rm = fmaxf(rm, __shfl_xor(rm, 4, 64));
                rm = fmaxf(rm, __shfl_xor(rm, 8, 64));
                float mn = fmaxf(m_st[mt][r], rm);
                float a  = __expf(fmaxf(m_st[mt][r] - mn, -88.0f));
                m_st[mt][r] = mn;
                al[mt][r] = a;
                float rs = 0.f;
                #pragma unroll
                for (int nt = 0; nt < 4; nt++) {
                    float p = __expf(fmaxf(s_acc[mt][nt][r] - mn, -88.0f));
                    s_acc[mt][nt][r] = p;
                    rs += p;
                }
                rs += __shfl_xor(rs, 1, 64);
                rs += __shfl_xor(rs, 2, 64);
                rs += __shfl_xor(rs, 4, 64);
                rs += __shfl_xor(rs, 8, 64);
                l_st[mt][r] = l_st[mt][r] * a + rs;
            }
        #pragma unroll
        for (int mt = 0; mt < 2; mt++)
            #pragma unroll
            for (int nt = 0; nt < 8; nt++)
                #pragma unroll
                for (int r = 0; r < 4; r++)
                    o_acc[mt][nt][r] *= al[mt][r];

        // P -> sP (wave-private rows; same wave reads them back)
        #pragma unroll
        for (int mt = 0; mt < 2; mt++)
            #pragma unroll
            for (int nt = 0; nt < 4; nt++)
                #pragma unroll
                for (int r = 0; r < 4; r++) {
                    int prow = wave * 32 + mt * 16 + fq * 4 + r;
                    int col  = nt * 16 + fr;
                    sP[prow * VPAD + col] = f2bf(s_acc[mt][nt][r]);
                }

        // O += P . V  (A = own P rows: m = wave*32+mt*16+fr, k = t; B: n = dh = nt*16+fr)
        #pragma unroll
        for (int kt = 0; kt < 2; kt++) {
            bf16x8 pf[2], vf[8];
            #pragma unroll
            for (int mt = 0; mt < 2; mt++)
                pf[mt] = *(const bf16x8_a*)(sP + (wave * 32 + mt * 16 + fr) * VPAD + kt * 32 + fq * 8);
            #pragma unroll
            for (int nt = 0; nt < 8; nt++)
                vf[nt] = *(const bf16x8_a*)(sV + (nt * 16 + fr) * VPAD + kt * 32 + fq * 8);
            #pragma unroll
            for (int mt = 0; mt < 2; mt++)
                #pragma unroll
                for (int nt = 0; nt < 8; nt++)
                    o_acc[mt][nt] = __builtin_amdgcn_mfma_f32_16x16x32_bf16(
                        pf[mt], vf[nt], o_acc[mt][nt], 0, 0, 0);
        }
    }

    // epilogue: O /= l, write transposed ctxT[dh][s], 4 consecutive s per lane (8B stores)
    #pragma unroll
    for (int mt = 0; mt < 2; mt++) {
        float inv[4];
        #pragma unroll
        for (int r = 0; r < 4; r++) inv[r] = 1.0f / l_st[mt][r];
        const int s0 = qt * 128 + wave * 32 + mt * 16 + fq * 4;
        #pragma unroll
        for (int nt = 0; nt < 8; nt++) {
            ushort4 w;
            w.x = f2b(o_acc[mt][nt][0] * inv[0]);
            w.y = f2b(o_acc[mt][nt][1] * inv[1]);
            w.z = f2b(o_acc[mt][nt][2] * inv[2]);
            w.w = f2b(o_acc[mt][nt][3] * inv[3]);
            int dh = nt * 16 + fr;
            *(ushort4_a*)(Cg + (size_t)dh * SEQ + s0) = w;
        }
    }
}

// =====================================================================
extern "C" void kernel_launch(void* const* d_in, const int* in_sizes, int n_in,
                              void* d_out, int out_size, void* d_ws, size_t ws_size,
                              hipStream_t stream)
{
    const void* x  = d_in[0];
    const void* Wq = d_in[1];
    const void* Wk = d_in[2];
    const void* Wv = d_in[3];
    const void* Wo = d_in[4];
    const void* fc = d_in[5];
    const void* fs = d_in[6];

    // workspace: 5 x 16MB bf16 [4096 x 2048] = 84 MB (same footprint as R2-4, known OK)
    char* ws = (char*)d_ws;
    const size_t BUF = (size_t)NB * SEQ * DIMN * 2;
    unsigned short* q_lin = (unsigned short*)(ws);
    unsigned short* k_lin = (unsigned short*)(ws + 1 * BUF);
    unsigned short* v_lin = (unsigned short*)(ws + 2 * BUF);
    unsigned short* vT    = (unsigned short*)(ws + 3 * BUF);
    unsigned short* ctxT  = (unsigned short*)(ws + 4 * BUF);

    dim3 blk(256);
    const long long SD = (long long)SEQ * DIMN;

    // q/k/v = x . W^T   [4096 x 2048 x 2048]; inputs follow flag, outputs bf16 ws
    dim3 g1(DIMN / 128, (NB * SEQ) / 128, 1);
    gemm_bt<<<g1, blk, 0, stream>>>(x, Wq, q_lin, fc, 1, 1, 0,
        DIMN, DIMN, DIMN, DIMN, 1, 0, 0, 0, 0, 0, 0, 1.0f);
    gemm_bt<<<g1, blk, 0, stream>>>(x, Wk, k_lin, fc, 1, 1, 0,
        DIMN, DIMN, DIMN, DIMN, 1, 0, 0, 0, 0, 0, 0, 1.0f);
    gemm_bt<<<g1, blk, 0, stream>>>(x, Wv, v_lin, fc, 1, 1, 0,
        DIMN, DIMN, DIMN, DIMN, 1, 0, 0, 0, 0, 0, 0, 1.0f);

    // RoPE on q,k in place (fc/fs dtype per flag)
    dim3 gr((NB * SEQ * DIMN / 2) / 256, 2, 1);
    rope_kernel<<<gr, blk, 0, stream>>>(q_lin, k_lin, fc, fs);

    // vT[b][h*128+dh][t] = v_lin[b][t][h*128+dh]
    dim3 gt(SEQ / 32, DIMN / 32, NB);
    transpose_kernel<<<gt, blk, 0, stream>>>(v_lin, vT);

    // fused causal attention -> ctxT[b][h*128+dh][s]
    dim3 gf(SEQ / 128, NB * NH, 1);
    flash_kernel<<<gf, blk, 0, stream>>>(q_lin, k_lin, vT, ctxT);

    // O[b][i][e] = sum_s ctxT[b][i][s] * Wo[e][s]; A bf16 ws, B+C follow flag
    dim3 gp(DIMN / 128, DIMN / 128, NB);
    gemm_bt<<<gp, blk, 0, stream>>>(ctxT, Wo, d_out, fc, 0, 1, 1,
        SEQ, SEQ, DIMN, DIMN, 1, SD, 0, 0, 0, (long long)DIMN * DIMN, 0, 1.0f);
}